// Round 1
// baseline (185.199 us; speedup 1.0000x reference)
//
#include <hip/hip_runtime.h>

// PatternDetector: B rows of L=256 int32 tokens in [0, 40).
// Per row: stable-compact nonzeros -> c[0..n-1]; count adjacent ==, >, <
// and lag-2 == over valid prefix; normalize; zero rows with n <= 1.
// One wave (64 lanes) per row. Memory-bound: ~130 MiB HBM traffic.

constexpr int L_SEQ = 256;
constexpr int WPB   = 4;   // waves per block (block = 256 threads)

__global__ __launch_bounds__(256, 4)
void pattern_kernel(const int* __restrict__ x, float* __restrict__ out, int rows)
{
    __shared__ int c_sh[WPB][L_SEQ];

    const int tid  = threadIdx.x;
    const int wave = tid >> 6;
    const int lane = tid & 63;
    const int row  = blockIdx.x * WPB + wave;
    const bool valid_row = (row < rows);
    const int  rr  = valid_row ? row : 0;

    // 1) One coalesced int4 per lane: the wave reads the entire 1 KiB row.
    const int4 v = ((const int4*)(x + (size_t)rr * L_SEQ))[lane];
    int vals[4] = { v.x, v.y, v.z, v.w };

    int cnt = 0;
    #pragma unroll
    for (int j = 0; j < 4; ++j) cnt += (vals[j] != 0);

    // 2) Inclusive prefix sum across the 64-lane wave.
    int pre = cnt;
    #pragma unroll
    for (int off = 1; off < 64; off <<= 1) {
        int t = __shfl_up(pre, off, 64);
        if (lane >= off) pre += t;
    }
    const int n = __shfl(pre, 63, 64);   // total nonzeros in this row
    int pos = pre - cnt;                 // exclusive prefix = my write offset

    int* const c = c_sh[wave];
    #pragma unroll
    for (int j = 0; j < 4; ++j) {
        if (vals[j] != 0) c[pos++] = vals[j];
    }
    __syncthreads();  // cheap; guarantees LDS write->read ordering

    // 3) Lane l evaluates compacted positions [4l, 4l+4).
    const int base = lane * 4;
    const int4 q = ((const int4*)c)[lane];           // c[base .. base+3], conflict-free b128
    // Neighbors c[base+4], c[base+5] live in the next lane's q.x, q.y.
    const int e0 = __shfl_down(q.x, 1, 64);
    const int e1 = __shfl_down(q.y, 1, 64);
    const int a0[6] = { q.x, q.y, q.z, q.w, e0, e1 };

    // Packed counters: rep | inc<<8 | dec<<16 | per<<24.
    // Each field's wave-total <= 255, so no cross-field carries.
    int packed = 0;
    #pragma unroll
    for (int j = 0; j < 4; ++j) {
        const int i  = base + j;
        const int a  = a0[j];
        const int b  = a0[j + 1];
        const int c2 = a0[j + 2];
        if (i < n - 1) {
            packed += (a == b) ? 1          : 0;
            packed += (b >  a) ? (1 << 8)   : 0;
            packed += (b <  a) ? (1 << 16)  : 0;
            if (i < n - 2) packed += (a == c2) ? (1 << 24) : 0;
        }
    }

    // 4) Wave reduction of the packed word (6 shuffles).
    #pragma unroll
    for (int off = 32; off >= 1; off >>= 1)
        packed += __shfl_down(packed, off, 64);

    // 5) Lane 0 writes the 4 features.
    if (lane == 0 && valid_row) {
        const int rep =  packed        & 0xFF;
        const int inc = (packed >> 8)  & 0xFF;
        const int dec = (packed >> 16) & 0xFF;
        const int per = (packed >> 24) & 0xFF;
        float4 o = make_float4(0.f, 0.f, 0.f, 0.f);
        if (n > 1) {
            const float d1 = (float)(n - 1);
            o.x = (float)rep / d1;
            o.y = (float)inc / d1;
            o.z = (float)dec / d1;
            if (n >= 4) o.w = (float)per / (float)(n - 2);
        }
        ((float4*)out)[row] = o;
    }
}

extern "C" void kernel_launch(void* const* d_in, const int* in_sizes, int n_in,
                              void* d_out, int out_size, void* d_ws, size_t ws_size,
                              hipStream_t stream) {
    const int* x  = (const int*)d_in[0];
    float*    out = (float*)d_out;
    const int rows   = in_sizes[0] / L_SEQ;
    const int blocks = (rows + WPB - 1) / WPB;
    pattern_kernel<<<dim3(blocks), dim3(256), 0, stream>>>(x, out, rows);
}

// Round 2
// 182.315 us; speedup vs baseline: 1.0158x; 1.0158x over previous
//
#include <hip/hip_runtime.h>

// PatternDetector: B rows of L=256 int32 tokens in [0, 40).
// Per row: stable-compact nonzeros -> c[0..n-1]; count adjacent ==, >, <
// and lag-2 == over valid prefix; normalize; zero rows with n <= 1.
// One wave (64 lanes) per row. Memory-bound target: ~21 us for 128 MiB.
// DS-pipe minimized: ballot+mbcnt for compaction offsets (VALU), DPP
// add-reduction for counters (VALU); LDS only for the value scatter/gather.

constexpr int L_SEQ = 256;
constexpr int WPB   = 4;   // waves per block (block = 256 threads)

__global__ __launch_bounds__(256, 4)
void pattern_kernel(const int* __restrict__ x, float* __restrict__ out, int rows)
{
    __shared__ int c_sh[WPB][L_SEQ];

    const int tid  = threadIdx.x;
    const int wave = tid >> 6;
    const int lane = tid & 63;
    const int row  = blockIdx.x * WPB + wave;
    const bool valid_row = (row < rows);
    const int  rr  = valid_row ? row : 0;

    // 1) One coalesced int4 per lane: the wave reads the entire 1 KiB row.
    const int4 v = ((const int4*)(x + (size_t)rr * L_SEQ))[lane];
    int vals[4] = { v.x, v.y, v.z, v.w };

    // 2) Compaction offsets via ballot + mbcnt (no DS-pipe traffic).
    //    Position of my slot-j value = #nonzeros strictly before (lane, j)
    //    = sum_j' mbcnt(mask_j') + #nonzero own slots j' < j.
    unsigned long long m0 = __ballot(vals[0] != 0);
    unsigned long long m1 = __ballot(vals[1] != 0);
    unsigned long long m2 = __ballot(vals[2] != 0);
    unsigned long long m3 = __ballot(vals[3] != 0);

    int below = 0;
    below = __builtin_amdgcn_mbcnt_hi((unsigned)(m0 >> 32),
            __builtin_amdgcn_mbcnt_lo((unsigned)m0, below));
    below = __builtin_amdgcn_mbcnt_hi((unsigned)(m1 >> 32),
            __builtin_amdgcn_mbcnt_lo((unsigned)m1, below));
    below = __builtin_amdgcn_mbcnt_hi((unsigned)(m2 >> 32),
            __builtin_amdgcn_mbcnt_lo((unsigned)m2, below));
    below = __builtin_amdgcn_mbcnt_hi((unsigned)(m3 >> 32),
            __builtin_amdgcn_mbcnt_lo((unsigned)m3, below));

    const int n = __popcll(m0) + __popcll(m1) + __popcll(m2) + __popcll(m3);

    // 3) Scatter nonzeros into this wave's private LDS slice.
    int pos = below;
    int* const c = c_sh[wave];
    #pragma unroll
    for (int j = 0; j < 4; ++j) {
        if (vals[j] != 0) c[pos++] = vals[j];
    }

    // Wave-private slice: only need THIS wave's DS writes complete before
    // its reads. No block barrier required.
    __asm__ volatile("s_waitcnt lgkmcnt(0)" ::: "memory");

    // 4) Lane l evaluates compacted positions [4l, 4l+4).
    const int base = lane * 4;
    const int4 q = ((const int4*)c)[lane];   // c[base..base+3], stride-16B b128: conflict-free
    // c[base+4], c[base+5] live in the next lane's q.x, q.y. (Lane 63's
    // results are garbage but provably never used: guards need n > 256.)
    const int e0 = __shfl_down(q.x, 1, 64);
    const int e1 = __shfl_down(q.y, 1, 64);
    const int a0[6] = { q.x, q.y, q.z, q.w, e0, e1 };

    // Packed counters: rep | inc<<8 | dec<<16 | per<<24.
    // Each field's wave-total <= 255, so no cross-field carries.
    int packed = 0;
    #pragma unroll
    for (int j = 0; j < 4; ++j) {
        const int i  = base + j;
        const int a  = a0[j];
        const int b  = a0[j + 1];
        const int c2 = a0[j + 2];
        if (i < n - 1) {
            packed += (a == b) ? 1          : 0;
            packed += (b >  a) ? (1 << 8)   : 0;
            packed += (b <  a) ? (1 << 16)  : 0;
            if (i < n - 2) packed += (a == c2) ? (1 << 24) : 0;
        }
    }

    // 5) Wave reduction on the VALU pipe via DPP (row_shr 1/2/4/8,
    //    row_bcast 15/31); total lands in lane 63.
    int vsum = packed;
    int t;
    t = __builtin_amdgcn_update_dpp(0, vsum, 0x111, 0xF, 0xF, true); vsum += t; // row_shr:1
    t = __builtin_amdgcn_update_dpp(0, vsum, 0x112, 0xF, 0xF, true); vsum += t; // row_shr:2
    t = __builtin_amdgcn_update_dpp(0, vsum, 0x114, 0xF, 0xE, true); vsum += t; // row_shr:4
    t = __builtin_amdgcn_update_dpp(0, vsum, 0x118, 0xF, 0xC, true); vsum += t; // row_shr:8
    t = __builtin_amdgcn_update_dpp(0, vsum, 0x142, 0xA, 0xF, true); vsum += t; // row_bcast:15
    t = __builtin_amdgcn_update_dpp(0, vsum, 0x143, 0xC, 0xF, true); vsum += t; // row_bcast:31

    // 6) Lane 63 holds the totals; write the 4 features.
    if (lane == 63 && valid_row) {
        const int rep =  vsum        & 0xFF;
        const int inc = (vsum >> 8)  & 0xFF;
        const int dec = (vsum >> 16) & 0xFF;
        const int per = (vsum >> 24) & 0xFF;
        float4 o = make_float4(0.f, 0.f, 0.f, 0.f);
        if (n > 1) {
            const float d1 = (float)(n - 1);
            o.x = (float)rep / d1;
            o.y = (float)inc / d1;
            o.z = (float)dec / d1;
            if (n >= 4) o.w = (float)per / (float)(n - 2);
        }
        ((float4*)out)[row] = o;
    }
}

extern "C" void kernel_launch(void* const* d_in, const int* in_sizes, int n_in,
                              void* d_out, int out_size, void* d_ws, size_t ws_size,
                              hipStream_t stream) {
    const int* x  = (const int*)d_in[0];
    float*    out = (float*)d_out;
    const int rows   = in_sizes[0] / L_SEQ;
    const int blocks = (rows + WPB - 1) / WPB;
    pattern_kernel<<<dim3(blocks), dim3(256), 0, stream>>>(x, out, rows);
}